// Round 1
// baseline (132.672 us; speedup 1.0000x reference)
//
#include <hip/hip_runtime.h>
#include <hip/hip_bf16.h>

constexpr int N = 16384;
constexpr int C = 64;    // NUM_CLUSTER
constexpr int D = 256;   // NUM_LATENT

// ---------------------------------------------------------------------------
// K0: ids[n] = argmax(mask[n, :])  (mask is one-hot, values 0.0/1.0)
// One wave per row; lane = cluster; ballot + ffs.
// ---------------------------------------------------------------------------
__global__ __launch_bounds__(256) void ids_kernel(const float* __restrict__ mask,
                                                  int* __restrict__ ids) {
    const int w    = threadIdx.x >> 6;
    const int lane = threadIdx.x & 63;
    const int n    = blockIdx.x * 4 + w;
    const float v  = mask[n * C + lane];
    const unsigned long long b = __ballot(v > 0.5f);
    if (lane == 0) ids[n] = __ffsll(b) - 1;
}

// ---------------------------------------------------------------------------
// K1: accumulate cluster sums + counts via global atomics.
// Block handles 64 rows; thread t handles dim t of each row (coalesced).
// Float-atomic ordering noise ~1e-7 relative, far below threshold.
// ---------------------------------------------------------------------------
__global__ __launch_bounds__(256) void accum_kernel(const float* __restrict__ X,
                                                    const int* __restrict__ ids,
                                                    float* __restrict__ sums,
                                                    int* __restrict__ counts) {
    const int tid  = threadIdx.x;
    const int row0 = blockIdx.x * 64;
    for (int r = 0; r < 64; ++r) {
        const int n  = row0 + r;
        const int id = ids[n];                       // wave-uniform (scalar load)
        atomicAdd(&sums[id * D + tid], X[n * D + tid]);
        if (tid == 0) atomicAdd(&counts[id], 1);
    }
}

// ---------------------------------------------------------------------------
// K2: muT[d][c] = sums[c][d] / counts[c]   (transposed layout so the main
// kernel's per-lane register staging is lane-coalesced)
// ---------------------------------------------------------------------------
__global__ __launch_bounds__(256) void finalize_kernel(const float* __restrict__ sums,
                                                       const int* __restrict__ counts,
                                                       float* __restrict__ muT) {
    const int c = blockIdx.x;
    const int d = threadIdx.x;
    const float inv = 1.0f / (float)counts[c];
    muT[d * C + c] = sums[c * D + d] * inv;
}

// ---------------------------------------------------------------------------
// K3: main distance + soft-assignment kernel.
// Block = 256 threads = 4 waves. lane = cluster c; wave w owns dims
// [64w, 64w+64) with mu chunk in 64 registers. X row staged in LDS and read
// via same-address broadcast float4. Cross-wave partials through small
// double-buffered LDS; wave 0 does q = 1/(1+dist), row-sum, write.
// ---------------------------------------------------------------------------
constexpr int ROWS_PER_BLOCK = 16;

__global__ __launch_bounds__(256) void dist_kernel(const float* __restrict__ X,
                                                   const float* __restrict__ muT,
                                                   float* __restrict__ out) {
    __shared__ float xrow[2][D];
    __shared__ float pd[2][4][C];

    const int tid  = threadIdx.x;
    const int w    = tid >> 6;
    const int lane = tid & 63;

    // Register-stage mu chunk: m[j] = mu[lane][64w + j] = muT[(64w+j)*C + lane]
    // (lane-coalesced global loads, all L2-hit: muT is 64 KB)
    float m[64];
    const float* muTw = muT + (w * 64) * C + lane;
#pragma unroll
    for (int j = 0; j < 64; ++j) m[j] = muTw[j * C];

    const int row0 = blockIdx.x * ROWS_PER_BLOCK;
    for (int r = 0; r < ROWS_PER_BLOCK; ++r) {
        const int n   = row0 + r;
        const int buf = r & 1;

        xrow[buf][tid] = X[n * D + tid];   // coalesced 1 KB/row
        __syncthreads();

        float acc = 0.0f;
#pragma unroll
        for (int j4 = 0; j4 < 16; ++j4) {
            const float4 xv = *reinterpret_cast<const float4*>(&xrow[buf][w * 64 + j4 * 4]);
            acc += fabsf(xv.x - m[4 * j4 + 0]);   // v_sub + v_add |src|
            acc += fabsf(xv.y - m[4 * j4 + 1]);
            acc += fabsf(xv.z - m[4 * j4 + 2]);
            acc += fabsf(xv.w - m[4 * j4 + 3]);
        }
        pd[buf][w][lane] = acc;
        __syncthreads();

        if (w == 0) {
            const float dist = pd[buf][0][lane] + pd[buf][1][lane] +
                               pd[buf][2][lane] + pd[buf][3][lane];
            const float q = 1.0f / (1.0f + dist);
            float s = q;
#pragma unroll
            for (int off = 1; off < 64; off <<= 1) s += __shfl_xor(s, off, 64);
            out[n * C + lane] = q / s;
        }
    }
}

// ---------------------------------------------------------------------------
// Workspace layout (bytes):
//   [0,      65536)  : sums   64*256 f32   (memset each call)
//   [65536,  65792)  : counts 64 i32       (memset each call)
//   [66560, 132096)  : muT    256*64 f32   (fully overwritten)
//   [132096,197632)  : ids    16384 i32    (fully overwritten)
// ---------------------------------------------------------------------------
extern "C" void kernel_launch(void* const* d_in, const int* in_sizes, int n_in,
                              void* d_out, int out_size, void* d_ws, size_t ws_size,
                              hipStream_t stream) {
    const float* X    = (const float*)d_in[0];
    const float* mask = (const float*)d_in[1];
    float* out        = (float*)d_out;

    char* ws       = (char*)d_ws;
    float* sums    = (float*)(ws);
    int*   counts  = (int*)(ws + 65536);
    float* muT     = (float*)(ws + 66560);
    int*   ids     = (int*)(ws + 132096);

    hipMemsetAsync(ws, 0, 66560, stream);

    ids_kernel<<<N / 4, 256, 0, stream>>>(mask, ids);
    accum_kernel<<<N / 64, 256, 0, stream>>>(X, ids, sums, counts);
    finalize_kernel<<<C, D, 0, stream>>>(sums, counts, muT);
    dist_kernel<<<N / ROWS_PER_BLOCK, 256, 0, stream>>>(X, muT, out);
}

// Round 2
// 123.775 us; speedup vs baseline: 1.0719x; 1.0719x over previous
//
#include <hip/hip_runtime.h>
#include <hip/hip_bf16.h>

constexpr int N = 16384;
constexpr int C = 64;     // NUM_CLUSTER
constexpr int D = 256;    // NUM_LATENT
constexpr int MAXB = 320; // bucket capacity per cluster (actual = 256)

// ---------------------------------------------------------------------------
// K0: bucket rows by cluster. One wave per row; lane = cluster; ballot+ffs,
// then ONE int atomic per row (16K atomics over 64 counters).
// ---------------------------------------------------------------------------
__global__ __launch_bounds__(256) void bucket_kernel(const float* __restrict__ mask,
                                                     int* __restrict__ bcount,
                                                     int* __restrict__ bucket) {
    const int w    = threadIdx.x >> 6;
    const int lane = threadIdx.x & 63;
    const int n    = blockIdx.x * 4 + w;
    const float v  = mask[n * C + lane];
    const unsigned long long b = __ballot(v > 0.5f);
    if (lane == 0) {
        const int id   = __ffsll(b) - 1;
        const int slot = atomicAdd(&bcount[id], 1);
        if (slot < MAXB) bucket[id * MAXB + slot] = n;
    }
}

// ---------------------------------------------------------------------------
// K1: gather-accumulate centroid sums. Block = (cluster c, quarter q).
// Thread t owns dim t with a REGISTER accumulator; row loads are coalesced
// 1 KB each, row indices come from the bucket (block-uniform -> s_load).
// Merge: 256 f32 atomics per block (4 contenders per address).
// ---------------------------------------------------------------------------
__global__ __launch_bounds__(256) void gather_kernel(const float* __restrict__ X,
                                                     const int* __restrict__ bcount,
                                                     const int* __restrict__ bucket,
                                                     float* __restrict__ musum) {
    const int tid = threadIdx.x;
    const int c   = blockIdx.x >> 2;
    const int q   = blockIdx.x & 3;
    const int base = q * 64;
    int nr = bcount[c] - base;
    nr = nr < 0 ? 0 : (nr > 64 ? 64 : nr);

    float acc = 0.0f;
#pragma unroll 8
    for (int i = 0; i < nr; ++i) {
        const int n = bucket[c * MAXB + base + i];  // block-uniform
        acc += X[n * D + tid];
    }
    atomicAdd(&musum[c * D + tid], acc);
}

// ---------------------------------------------------------------------------
// K2: muT[d][c] = musum[c][d] / count[c]  (transposed so the dist kernel's
// per-lane register staging is lane-coalesced)
// ---------------------------------------------------------------------------
__global__ __launch_bounds__(256) void finalize_kernel(const float* __restrict__ musum,
                                                       const int* __restrict__ bcount,
                                                       float* __restrict__ muT) {
    const int c = blockIdx.x;
    const int d = threadIdx.x;
    const float inv = 1.0f / (float)bcount[c];
    muT[d * C + c] = musum[c * D + d] * inv;
}

// ---------------------------------------------------------------------------
// K3: main distance + soft-assignment kernel.
// Block = 256 threads = 4 waves. lane = cluster c; wave w owns dims
// [64w, 64w+64) with mu chunk in 64 registers. X row staged in LDS and read
// via same-address broadcast float4. Cross-wave partials through small
// double-buffered LDS; finishing wave rotates per row (r & 3).
// ---------------------------------------------------------------------------
constexpr int ROWS_PER_BLOCK = 16;

__global__ __launch_bounds__(256) void dist_kernel(const float* __restrict__ X,
                                                   const float* __restrict__ muT,
                                                   float* __restrict__ out) {
    __shared__ float xrow[2][D];
    __shared__ float pd[2][4][C];

    const int tid  = threadIdx.x;
    const int w    = tid >> 6;
    const int lane = tid & 63;

    // Register-stage mu chunk: m[j] = mu[lane][64w + j] = muT[(64w+j)*C + lane]
    // (lane-coalesced global loads, all L2-hit: muT is 64 KB)
    float m[64];
    const float* muTw = muT + (w * 64) * C + lane;
#pragma unroll
    for (int j = 0; j < 64; ++j) m[j] = muTw[j * C];

    const int row0 = blockIdx.x * ROWS_PER_BLOCK;
    for (int r = 0; r < ROWS_PER_BLOCK; ++r) {
        const int n   = row0 + r;
        const int buf = r & 1;

        xrow[buf][tid] = X[n * D + tid];   // coalesced 1 KB/row
        __syncthreads();

        float acc = 0.0f;
#pragma unroll
        for (int j4 = 0; j4 < 16; ++j4) {
            const float4 xv = *reinterpret_cast<const float4*>(&xrow[buf][w * 64 + j4 * 4]);
            acc += fabsf(xv.x - m[4 * j4 + 0]);   // v_sub + v_add |src|
            acc += fabsf(xv.y - m[4 * j4 + 1]);
            acc += fabsf(xv.z - m[4 * j4 + 2]);
            acc += fabsf(xv.w - m[4 * j4 + 3]);
        }
        pd[buf][w][lane] = acc;
        __syncthreads();

        if (w == (r & 3)) {                // rotate the finishing wave
            const float dist = pd[buf][0][lane] + pd[buf][1][lane] +
                               pd[buf][2][lane] + pd[buf][3][lane];
            const float q = 1.0f / (1.0f + dist);
            float s = q;
#pragma unroll
            for (int off = 1; off < 64; off <<= 1) s += __shfl_xor(s, off, 64);
            out[n * C + lane] = q / s;
        }
    }
}

// ---------------------------------------------------------------------------
// Workspace layout (bytes):
//   [0,      256)    : bcount 64 i32            (memset each call)
//   [1024,   66560)  : musum  64*256 f32        (memset each call)
//   [66560, 148480)  : bucket 64*320 i32        (written via bucketing)
//   [148480,214016)  : muT    256*64 f32        (fully overwritten)
// ---------------------------------------------------------------------------
extern "C" void kernel_launch(void* const* d_in, const int* in_sizes, int n_in,
                              void* d_out, int out_size, void* d_ws, size_t ws_size,
                              hipStream_t stream) {
    const float* X    = (const float*)d_in[0];
    const float* mask = (const float*)d_in[1];
    float* out        = (float*)d_out;

    char*  ws     = (char*)d_ws;
    int*   bcount = (int*)(ws);
    float* musum  = (float*)(ws + 1024);
    int*   bucket = (int*)(ws + 66560);
    float* muT    = (float*)(ws + 148480);

    hipMemsetAsync(ws, 0, 66560, stream);  // bcount + musum

    bucket_kernel<<<N / 4, 256, 0, stream>>>(mask, bcount, bucket);
    gather_kernel<<<C * 4, 256, 0, stream>>>(X, bcount, bucket, musum);
    finalize_kernel<<<C, D, 0, stream>>>(musum, bcount, muT);
    dist_kernel<<<N / ROWS_PER_BLOCK, 256, 0, stream>>>(X, muT, out);
}

// Round 3
// 77.873 us; speedup vs baseline: 1.7037x; 1.5895x over previous
//
#include <hip/hip_runtime.h>
#include <hip/hip_bf16.h>

constexpr int N = 16384;
constexpr int C = 64;     // NUM_CLUSTER
constexpr int D = 256;    // NUM_LATENT
constexpr int PMAX = 256; // max partial-sum chunks

// ---------------------------------------------------------------------------
// K0: ids[n] = argmax(mask[n,:]) via ballot. One wave per row.
// ---------------------------------------------------------------------------
__global__ __launch_bounds__(256) void ids_kernel(const float* __restrict__ mask,
                                                  int* __restrict__ ids) {
    const int w    = threadIdx.x >> 6;
    const int lane = threadIdx.x & 63;
    const int n    = blockIdx.x * 4 + w;
    const unsigned long long b = __ballot(mask[n * C + lane] > 0.5f);
    if (lane == 0) ids[n] = __ffsll(b) - 1;
}

// ---------------------------------------------------------------------------
// K1: per-chunk partial centroid sums. Block p owns rows [p*R,(p+1)*R).
// Accumulate into private LDS [64][256] via ds_add_f32 (no-return LDS atomic:
// no RMW latency chain, no global atomics). Bank: lsum[id*256+tid] -> 2-way
// aliasing = free. Dump 64 KB partial coalesced at the end.
// ---------------------------------------------------------------------------
__global__ __launch_bounds__(256) void psum_kernel(const float* __restrict__ X,
                                                   const int* __restrict__ ids,
                                                   float* __restrict__ partials,
                                                   int* __restrict__ pcountT,
                                                   int P) {
    __shared__ float lsum[C * D];   // 64 KB
    __shared__ int   lcnt[C];
    const int tid  = threadIdx.x;
    const int p    = blockIdx.x;
    const int R    = N / P;
    const int row0 = p * R;

#pragma unroll
    for (int i = 0; i < (C * D) / (256 * 4); ++i)    // 16 x float4 per thread
        ((float4*)lsum)[tid + i * 256] = float4{0.f, 0.f, 0.f, 0.f};
    if (tid < C) lcnt[tid] = 0;
    __syncthreads();

    for (int r = 0; r < R; ++r) {
        const int n  = row0 + r;
        const int id = ids[n];                              // block-uniform
        atomicAdd(&lsum[id * D + tid], X[(size_t)n * D + tid]);  // ds_add_f32
        if (tid == 0) atomicAdd(&lcnt[id], 1);
    }
    __syncthreads();

    float* dst = partials + (size_t)p * (C * D);
#pragma unroll
    for (int i = 0; i < (C * D) / (256 * 4); ++i)
        ((float4*)dst)[tid + i * 256] = ((const float4*)lsum)[tid + i * 256];
    if (tid < C) pcountT[tid * P + p] = lcnt[tid];
}

// ---------------------------------------------------------------------------
// K2: muT[d][c] = (sum_p partials[p][c][d]) / count[c].
// Block b covers 64 consecutive flat (c,d) pairs (c uniform per block);
// wave w strides p. Coalesced 256 B reads of partials.
// ---------------------------------------------------------------------------
__global__ __launch_bounds__(256) void reduce_kernel(const float* __restrict__ partials,
                                                     const int* __restrict__ pcountT,
                                                     float* __restrict__ muT,
                                                     int P) {
    __shared__ float redf[4][64];
    __shared__ int   redi[4];
    const int tid  = threadIdx.x;
    const int w    = tid >> 6;
    const int lane = tid & 63;
    const int pair = blockIdx.x * 64 + lane;  // flat c*D + d
    const int c    = pair >> 8;               // uniform within block
    const int d    = pair & 255;

    float s = 0.f;
    for (int p = w; p < P; p += 4) s += partials[(size_t)p * (C * D) + pair];

    int ci = 0;
    if (lane == 0)
        for (int p = w; p < P; p += 4) ci += pcountT[c * P + p];

    redf[w][lane] = s;
    if (lane == 0) redi[w] = ci;
    __syncthreads();
    if (w == 0) {
        const float tot = redf[0][lane] + redf[1][lane] + redf[2][lane] + redf[3][lane];
        const int   cnt = redi[0] + redi[1] + redi[2] + redi[3];
        muT[d * C + c] = tot / (float)cnt;
    }
}

// ---------------------------------------------------------------------------
// K3: distances + soft assignment. lane = cluster; wave w owns dims
// [64w,64w+64) with mu in 64 registers. x read straight from global with
// wave-uniform (broadcast/scalar) float4 loads — no LDS staging. 4 rows per
// batch (ILP-4 acc chains), ONE barrier per batch, all 4 waves finish one
// row each in parallel. pd double-buffered so no second barrier is needed.
// ---------------------------------------------------------------------------
constexpr int RPB = 16;

__global__ __launch_bounds__(256) void dist_kernel(const float* __restrict__ X,
                                                   const float* __restrict__ muT,
                                                   float* __restrict__ out) {
    __shared__ float pd[2][4][4][C];   // [buf][writer_wave][row][cluster]
    const int tid  = threadIdx.x;
    const int w    = __builtin_amdgcn_readfirstlane(tid >> 6);  // provably uniform
    const int lane = tid & 63;

    // mu chunk in registers: m[j] = mu[lane][64w+j] (lane-coalesced, L2-hot)
    float m[64];
    const float* muTw = muT + (w * 64) * C + lane;
#pragma unroll
    for (int j = 0; j < 64; ++j) m[j] = muTw[j * C];

    const int row0 = blockIdx.x * RPB;
#pragma unroll 1
    for (int k = 0; k < RPB / 4; ++k) {
        const int buf = k & 1;
        const int rb  = row0 + k * 4;
        const float* x0 = X + (size_t)(rb + 0) * D + w * 64;  // wave-uniform addr
        const float* x1 = x0 + D;
        const float* x2 = x0 + 2 * D;
        const float* x3 = x0 + 3 * D;
        float a0 = 0.f, a1 = 0.f, a2 = 0.f, a3 = 0.f;
#pragma unroll
        for (int j4 = 0; j4 < 16; ++j4) {
            const float4 v0 = *(const float4*)(x0 + j4 * 4);
            const float4 v1 = *(const float4*)(x1 + j4 * 4);
            const float4 v2 = *(const float4*)(x2 + j4 * 4);
            const float4 v3 = *(const float4*)(x3 + j4 * 4);
            const float m0 = m[j4 * 4 + 0], m1 = m[j4 * 4 + 1];
            const float m2 = m[j4 * 4 + 2], m3 = m[j4 * 4 + 3];
            a0 += fabsf(v0.x - m0) + fabsf(v0.y - m1) + fabsf(v0.z - m2) + fabsf(v0.w - m3);
            a1 += fabsf(v1.x - m0) + fabsf(v1.y - m1) + fabsf(v1.z - m2) + fabsf(v1.w - m3);
            a2 += fabsf(v2.x - m0) + fabsf(v2.y - m1) + fabsf(v2.z - m2) + fabsf(v2.w - m3);
            a3 += fabsf(v3.x - m0) + fabsf(v3.y - m1) + fabsf(v3.z - m2) + fabsf(v3.w - m3);
        }
        pd[buf][w][0][lane] = a0;
        pd[buf][w][1][lane] = a1;
        pd[buf][w][2][lane] = a2;
        pd[buf][w][3][lane] = a3;
        __syncthreads();
        // finish: wave w owns row rb+w (all waves busy, no second barrier:
        // next iteration writes pd[buf^1])
        const float dist = pd[buf][0][w][lane] + pd[buf][1][w][lane]
                         + pd[buf][2][w][lane] + pd[buf][3][w][lane];
        const float q = 1.0f / (1.0f + dist);
        float ssum = q;
#pragma unroll
        for (int off = 1; off < 64; off <<= 1) ssum += __shfl_xor(ssum, off, 64);
        out[(size_t)(rb + w) * C + lane] = q / ssum;
    }
}

// ---------------------------------------------------------------------------
// Workspace layout (bytes):
//   [0,      65536)  : ids      16384 i32
//   [65536, 131072)  : muT      256*64 f32
//   [131072,196608)  : pcountT  64*PMAX i32
//   [196608, ...  )  : partials P*64*256 f32  (P picked from ws_size)
// No memsets needed: every buffer is fully written before it is read.
// ---------------------------------------------------------------------------
extern "C" void kernel_launch(void* const* d_in, const int* in_sizes, int n_in,
                              void* d_out, int out_size, void* d_ws, size_t ws_size,
                              hipStream_t stream) {
    const float* X    = (const float*)d_in[0];
    const float* mask = (const float*)d_in[1];
    float* out        = (float*)d_out;

    char*  ws       = (char*)d_ws;
    int*   ids      = (int*)(ws);
    float* muT      = (float*)(ws + 65536);
    int*   pcountT  = (int*)(ws + 131072);
    float* partials = (float*)(ws + 196608);

    const size_t base = 196608;
    const size_t slab = (size_t)C * D * 4;   // 64 KB per partial set
    int P = 2;
    if      (ws_size >= base + 256 * slab) P = 256;
    else if (ws_size >= base + 128 * slab) P = 128;
    else if (ws_size >= base + 32 * slab)  P = 32;
    else if (ws_size >= base + 8 * slab)   P = 8;

    ids_kernel   <<<N / 4,        256, 0, stream>>>(mask, ids);
    psum_kernel  <<<P,            256, 0, stream>>>(X, ids, partials, pcountT, P);
    reduce_kernel<<<(C * D) / 64, 256, 0, stream>>>(partials, pcountT, muT, P);
    dist_kernel  <<<N / RPB,      256, 0, stream>>>(X, muT, out);
}